// Round 1
// baseline (346.931 us; speedup 1.0000x reference)
//
#include <hip/hip_runtime.h>
#include <math.h>

namespace {

constexpr int kB = 32;
constexpr int kS = 4096;
constexpr int kD = 2048;
constexpr int kTile = 16;   // rows per online-softmax tile (re-read distance = 128 KB/block)

// Pass 1: per (batch, chunk) partial flash-style softmax-weighted sum.
// grid = (nchunk, B), block = 256 threads (4 waves).
// Thread d-mapping (score phase, per wave): lane reads float4 at d = 256*k + 4*lane.
// Thread d-mapping (accumulate + output): thread t owns d in [4t,4t+4) u [1024+4t, 1024+4t+4).
__global__ __launch_bounds__(256, 4)
void attn_partial(const float* __restrict__ h,      // [B, D]
                  const float* __restrict__ E,      // [B, S, D]
                  float* __restrict__ acc_ws,       // [B, nchunk, D]
                  float* __restrict__ ml_ws,        // [B, nchunk, 2] (m, l)
                  int nchunk)
{
    const int c    = blockIdx.x;
    const int b    = blockIdx.y;
    const int t    = threadIdx.x;
    const int lane = t & 63;
    const int wave = t >> 6;
    const int cs   = kS / nchunk;     // rows per chunk
    const int s0   = c * cs;

    __shared__ float s_scores[kTile];

    // decoder_hidden slice for this lane's score-phase mapping, in registers
    const float* hb = h + (size_t)b * kD;
    float4 hreg[8];
#pragma unroll
    for (int k = 0; k < 8; ++k)
        hreg[k] = *reinterpret_cast<const float4*>(hb + 256 * k + 4 * lane);

    float a0x = 0, a0y = 0, a0z = 0, a0w = 0;
    float a1x = 0, a1y = 0, a1z = 0, a1w = 0;
    float m = -INFINITY, l = 0.f;

    const float* Eb = E + (size_t)b * kS * kD;

    for (int tile0 = 0; tile0 < cs; tile0 += kTile) {
        // ---- score phase: wave w handles rows w, w+4, ... within the tile ----
#pragma unroll
        for (int r = wave; r < kTile; r += 4) {
            const float* row = Eb + (size_t)(s0 + tile0 + r) * kD + 4 * lane;
            float p = 0.f;
#pragma unroll
            for (int k = 0; k < 8; ++k) {
                float4 e = *reinterpret_cast<const float4*>(row + 256 * k);
                p += e.x * hreg[k].x + e.y * hreg[k].y + e.z * hreg[k].z + e.w * hreg[k].w;
            }
            // wave-64 shuffle reduction
#pragma unroll
            for (int off = 32; off > 0; off >>= 1)
                p += __shfl_down(p, off, 64);
            if (lane == 0) s_scores[r] = p;
        }
        __syncthreads();

        // ---- online softmax update ----
        float tmax = -INFINITY;
#pragma unroll
        for (int r = 0; r < kTile; ++r) tmax = fmaxf(tmax, s_scores[r]);
        const float mnew  = fmaxf(m, tmax);
        const float scale = __expf(m - mnew);   // first iter: exp(-inf) = 0
        a0x *= scale; a0y *= scale; a0z *= scale; a0w *= scale;
        a1x *= scale; a1y *= scale; a1z *= scale; a1w *= scale;
        l *= scale;

        // ---- accumulate phase: re-read tile rows (L2/L3-hot), FMA into regs ----
        const float* base0 = Eb + (size_t)(s0 + tile0) * kD + 4 * t;
#pragma unroll
        for (int r = 0; r < kTile; ++r) {
            const float w = __expf(s_scores[r] - mnew);
            l += w;
            const float* row = base0 + (size_t)r * kD;
            float4 e0 = *reinterpret_cast<const float4*>(row);
            float4 e1 = *reinterpret_cast<const float4*>(row + 1024);
            a0x += w * e0.x; a0y += w * e0.y; a0z += w * e0.z; a0w += w * e0.w;
            a1x += w * e1.x; a1y += w * e1.y; a1z += w * e1.z; a1w += w * e1.w;
        }
        m = mnew;
        __syncthreads();   // s_scores reused next tile
    }

    float* aout = acc_ws + ((size_t)b * nchunk + c) * kD;
    float4 o0 = {a0x, a0y, a0z, a0w};
    float4 o1 = {a1x, a1y, a1z, a1w};
    *reinterpret_cast<float4*>(aout + 4 * t)        = o0;
    *reinterpret_cast<float4*>(aout + 1024 + 4 * t) = o1;
    if (t == 0) {
        ml_ws[((size_t)b * nchunk + c) * 2 + 0] = m;
        ml_ws[((size_t)b * nchunk + c) * 2 + 1] = l;
    }
}

// Pass 2: exact cross-chunk softmax combine. grid = B, block = 256.
__global__ __launch_bounds__(256)
void attn_combine(const float* __restrict__ acc_ws,
                  const float* __restrict__ ml_ws,
                  float* __restrict__ out,
                  int nchunk)
{
    const int b = blockIdx.x;
    const int t = threadIdx.x;

    float M = -INFINITY;
    for (int c = 0; c < nchunk; ++c)
        M = fmaxf(M, ml_ws[((size_t)b * nchunk + c) * 2 + 0]);
    float L = 0.f;
    for (int c = 0; c < nchunk; ++c)
        L += ml_ws[((size_t)b * nchunk + c) * 2 + 1] *
             __expf(ml_ws[((size_t)b * nchunk + c) * 2 + 0] - M);

    float o0x = 0, o0y = 0, o0z = 0, o0w = 0;
    float o1x = 0, o1y = 0, o1z = 0, o1w = 0;
    for (int c = 0; c < nchunk; ++c) {
        const float coef = __expf(ml_ws[((size_t)b * nchunk + c) * 2 + 0] - M);
        const float* a = acc_ws + ((size_t)b * nchunk + c) * kD;
        float4 a0 = *reinterpret_cast<const float4*>(a + 4 * t);
        float4 a1 = *reinterpret_cast<const float4*>(a + 1024 + 4 * t);
        o0x += coef * a0.x; o0y += coef * a0.y; o0z += coef * a0.z; o0w += coef * a0.w;
        o1x += coef * a1.x; o1y += coef * a1.y; o1z += coef * a1.z; o1w += coef * a1.w;
    }
    const float inv = 1.f / L;
    float* ob = out + (size_t)b * kD;
    float4 r0 = {o0x * inv, o0y * inv, o0z * inv, o0w * inv};
    float4 r1 = {o1x * inv, o1y * inv, o1z * inv, o1w * inv};
    *reinterpret_cast<float4*>(ob + 4 * t)        = r0;
    *reinterpret_cast<float4*>(ob + 1024 + 4 * t) = r1;
}

} // namespace

extern "C" void kernel_launch(void* const* d_in, const int* in_sizes, int n_in,
                              void* d_out, int out_size, void* d_ws, size_t ws_size,
                              hipStream_t stream) {
    const float* h = (const float*)d_in[0];   // decoder_hidden [B, D]
    const float* E = (const float*)d_in[1];   // encoder_states [B, S, D]
    float* out = (float*)d_out;

    // pick largest power-of-two chunk count whose partials fit in d_ws
    int nchunk = 32;
    while (nchunk > 1 &&
           (size_t)kB * nchunk * (kD + 2) * sizeof(float) > ws_size)
        nchunk >>= 1;

    float* acc_ws = (float*)d_ws;                          // [B, nchunk, D]
    float* ml_ws  = acc_ws + (size_t)kB * nchunk * kD;     // [B, nchunk, 2]

    dim3 g1(nchunk, kB);
    attn_partial<<<g1, 256, 0, stream>>>(h, E, acc_ws, ml_ws, nchunk);
    attn_combine<<<kB, 256, 0, stream>>>(acc_ws, ml_ws, out, nchunk);
}

// Round 2
// 278.087 us; speedup vs baseline: 1.2476x; 1.2476x over previous
//
#include <hip/hip_runtime.h>
#include <math.h>

namespace {

constexpr int kB = 32;
constexpr int kS = 4096;
constexpr int kD = 2048;
constexpr int kNW = 4;   // waves per block

// Pass 1: single-read flash partial. grid = (nchunk, B), block = 256 (4 waves).
// Each wave owns rows {wave, wave+4, ...} of its chunk. A wave's 64 lanes hold a
// full row in registers (lane covers d = 256*k + 4*lane, k=0..7), so the row is
// read from HBM exactly once: dot -> butterfly reduce -> online-softmax FMA.
__global__ __launch_bounds__(256, 4)
void attn_partial(const float* __restrict__ h,      // [B, D]
                  const float* __restrict__ E,      // [B, S, D]
                  float* __restrict__ acc_ws,       // [B, nchunk, kNW, D]
                  float* __restrict__ ml_ws,        // [B, nchunk, kNW, 2]
                  int nchunk)
{
    const int c    = blockIdx.x;
    const int b    = blockIdx.y;
    const int t    = threadIdx.x;
    const int lane = t & 63;
    const int wave = t >> 6;
    const int cs   = kS / nchunk;     // rows per chunk
    const int s0   = c * cs;

    const float* hb = h + (size_t)b * kD;
    float4 hreg[8];
#pragma unroll
    for (int k = 0; k < 8; ++k)
        hreg[k] = *reinterpret_cast<const float4*>(hb + 256 * k + 4 * lane);

    float4 acc[8];
#pragma unroll
    for (int k = 0; k < 8; ++k) acc[k] = make_float4(0.f, 0.f, 0.f, 0.f);
    float m = -INFINITY, l = 0.f;

    const float* Eb = E + ((size_t)b * kS + s0) * kD + 4 * lane;

    for (int r = wave; r < cs; r += kNW) {
        const float* row = Eb + (size_t)r * kD;
        float4 e[8];
#pragma unroll
        for (int k = 0; k < 8; ++k)
            e[k] = *reinterpret_cast<const float4*>(row + 256 * k);

        float p = 0.f;
#pragma unroll
        for (int k = 0; k < 8; ++k)
            p += e[k].x * hreg[k].x + e[k].y * hreg[k].y +
                 e[k].z * hreg[k].z + e[k].w * hreg[k].w;

        // butterfly: all 64 lanes end with the bit-identical row score
#pragma unroll
        for (int off = 32; off > 0; off >>= 1)
            p += __shfl_xor(p, off, 64);

        float w;
        if (p > m) {                       // wave-uniform branch; rare (~ln(rows))
            const float scale = __expf(m - p);   // first hit: exp(-inf)=0
#pragma unroll
            for (int k = 0; k < 8; ++k) {
                acc[k].x *= scale; acc[k].y *= scale;
                acc[k].z *= scale; acc[k].w *= scale;
            }
            l *= scale;
            m = p;
            w = 1.f;
        } else {
            w = __expf(p - m);
        }
        l += w;
#pragma unroll
        for (int k = 0; k < 8; ++k) {
            acc[k].x += w * e[k].x; acc[k].y += w * e[k].y;
            acc[k].z += w * e[k].z; acc[k].w += w * e[k].w;
        }
    }

    float* aout = acc_ws + (((size_t)b * nchunk + c) * kNW + wave) * kD;
#pragma unroll
    for (int k = 0; k < 8; ++k)
        *reinterpret_cast<float4*>(aout + 256 * k + 4 * lane) = acc[k];
    if (lane == 0) {
        float* ml = ml_ws + (((size_t)b * nchunk + c) * kNW + wave) * 2;
        ml[0] = m;
        ml[1] = l;
    }
}

// Pass 2: exact cross-partial softmax combine. grid = B, block = 256.
// np = nchunk * kNW partials per batch.
__global__ __launch_bounds__(256)
void attn_combine(const float* __restrict__ acc_ws,
                  const float* __restrict__ ml_ws,
                  float* __restrict__ out,
                  int np)
{
    const int b = blockIdx.x;
    const int t = threadIdx.x;

    float M = -INFINITY;
    for (int p = 0; p < np; ++p)
        M = fmaxf(M, ml_ws[((size_t)b * np + p) * 2 + 0]);

    float L = 0.f;
    float4 o0 = {0.f, 0.f, 0.f, 0.f};
    float4 o1 = {0.f, 0.f, 0.f, 0.f};
    for (int p = 0; p < np; ++p) {
        const float mp = ml_ws[((size_t)b * np + p) * 2 + 0];
        const float lp = ml_ws[((size_t)b * np + p) * 2 + 1];
        const float coef = __expf(mp - M);
        L += lp * coef;
        const float* a = acc_ws + ((size_t)b * np + p) * kD;
        float4 a0 = *reinterpret_cast<const float4*>(a + 4 * t);
        float4 a1 = *reinterpret_cast<const float4*>(a + 1024 + 4 * t);
        o0.x += coef * a0.x; o0.y += coef * a0.y;
        o0.z += coef * a0.z; o0.w += coef * a0.w;
        o1.x += coef * a1.x; o1.y += coef * a1.y;
        o1.z += coef * a1.z; o1.w += coef * a1.w;
    }
    const float inv = 1.f / L;
    float* ob = out + (size_t)b * kD;
    float4 r0 = {o0.x * inv, o0.y * inv, o0.z * inv, o0.w * inv};
    float4 r1 = {o1.x * inv, o1.y * inv, o1.z * inv, o1.w * inv};
    *reinterpret_cast<float4*>(ob + 4 * t)        = r0;
    *reinterpret_cast<float4*>(ob + 1024 + 4 * t) = r1;
}

} // namespace

extern "C" void kernel_launch(void* const* d_in, const int* in_sizes, int n_in,
                              void* d_out, int out_size, void* d_ws, size_t ws_size,
                              hipStream_t stream) {
    const float* h = (const float*)d_in[0];   // decoder_hidden [B, D]
    const float* E = (const float*)d_in[1];   // encoder_states [B, S, D]
    float* out = (float*)d_out;

    // largest power-of-two chunk count whose per-wave partials fit in d_ws
    int nchunk = 32;
    while (nchunk > 1 &&
           (size_t)kB * nchunk * kNW * (kD + 2) * sizeof(float) > ws_size)
        nchunk >>= 1;

    float* acc_ws = (float*)d_ws;                              // [B, nchunk, kNW, D]
    float* ml_ws  = acc_ws + (size_t)kB * nchunk * kNW * kD;   // [B, nchunk, kNW, 2]

    dim3 g1(nchunk, kB);
    attn_partial<<<g1, 256, 0, stream>>>(h, E, acc_ws, ml_ws, nchunk);
    attn_combine<<<kB, 256, 0, stream>>>(acc_ws, ml_ws, out, nchunk * kNW);
}

// Round 3
// 218.920 us; speedup vs baseline: 1.5847x; 1.2703x over previous
//
#include <hip/hip_runtime.h>
#include <math.h>

namespace {

constexpr int kB = 32;
constexpr int kS = 4096;
constexpr int kD = 2048;
constexpr int kNW = 4;   // waves per block

// Pass 1: single-read flash partial with register double-buffering.
// grid = (nchunk, B), block = 256 (4 independent waves; no syncthreads).
// Wave w owns rows {w, w+4, ...} of its chunk; a row lives entirely in the
// wave's registers (lane covers d = 256*k + 4*lane). Rotated 2-deep pipeline:
// while row i is reduced/accumulated, row i+2's loads are in flight.
__global__ __launch_bounds__(256, 2)
void attn_partial(const float* __restrict__ h,      // [B, D]
                  const float* __restrict__ E,      // [B, S, D]
                  float* __restrict__ acc_ws,       // [B, nchunk, kNW, D]
                  float* __restrict__ ml_ws,        // [B, nchunk, kNW, 2]
                  int nchunk)
{
    const int c    = blockIdx.x;
    const int b    = blockIdx.y;
    const int t    = threadIdx.x;
    const int lane = t & 63;
    const int wave = t >> 6;
    const int cs   = kS / nchunk;     // rows per chunk (multiple of 8)
    const int s0   = c * cs;
    const int n    = cs / kNW;        // rows per wave (even)

    const float* hb = h + (size_t)b * kD;
    float4 hreg[8];
#pragma unroll
    for (int k = 0; k < 8; ++k)
        hreg[k] = *reinterpret_cast<const float4*>(hb + 256 * k + 4 * lane);

    float4 acc[8];
#pragma unroll
    for (int k = 0; k < 8; ++k) acc[k] = make_float4(0.f, 0.f, 0.f, 0.f);
    float m = -INFINITY, l = 0.f;

    // row i (0-based per wave) lives at Eb + i*kNW*kD
    const float* Eb = E + ((size_t)b * kS + s0 + wave) * kD + 4 * lane;

    float4 e0[8], e1[8];

#define LOAD(buf, i)                                                         \
    {                                                                        \
        const float* _row = Eb + (size_t)(i) * (kNW * kD);                   \
        _Pragma("unroll")                                                    \
        for (int k = 0; k < 8; ++k)                                          \
            buf[k] = *reinterpret_cast<const float4*>(_row + 256 * k);       \
    }

#define COMPUTE(buf)                                                         \
    {                                                                        \
        float p = 0.f;                                                       \
        _Pragma("unroll")                                                    \
        for (int k = 0; k < 8; ++k)                                          \
            p += buf[k].x * hreg[k].x + buf[k].y * hreg[k].y +               \
                 buf[k].z * hreg[k].z + buf[k].w * hreg[k].w;                \
        _Pragma("unroll")                                                    \
        for (int off = 32; off > 0; off >>= 1)                               \
            p += __shfl_xor(p, off, 64);                                     \
        float w;                                                             \
        if (p > m) { /* wave-uniform; rare */                                \
            const float scale = __expf(m - p);                               \
            _Pragma("unroll")                                                \
            for (int k = 0; k < 8; ++k) {                                    \
                acc[k].x *= scale; acc[k].y *= scale;                        \
                acc[k].z *= scale; acc[k].w *= scale;                        \
            }                                                                \
            l *= scale;                                                      \
            m = p;                                                           \
            w = 1.f;                                                         \
        } else {                                                             \
            w = __expf(p - m);                                               \
        }                                                                    \
        l += w;                                                              \
        _Pragma("unroll")                                                    \
        for (int k = 0; k < 8; ++k) {                                        \
            acc[k].x += w * buf[k].x; acc[k].y += w * buf[k].y;              \
            acc[k].z += w * buf[k].z; acc[k].w += w * buf[k].w;              \
        }                                                                    \
    }

    // rotated 2-deep pipeline; n is even and >= 2
    LOAD(e0, 0);
    LOAD(e1, 1);
    for (int i = 0; i < n - 2; i += 2) {
        COMPUTE(e0);
        LOAD(e0, i + 2);
        COMPUTE(e1);
        LOAD(e1, i + 3);
    }
    COMPUTE(e0);
    COMPUTE(e1);

#undef LOAD
#undef COMPUTE

    float* aout = acc_ws + (((size_t)b * nchunk + c) * kNW + wave) * kD;
#pragma unroll
    for (int k = 0; k < 8; ++k)
        *reinterpret_cast<float4*>(aout + 256 * k + 4 * lane) = acc[k];
    if (lane == 0) {
        float* ml = ml_ws + (((size_t)b * nchunk + c) * kNW + wave) * 2;
        ml[0] = m;
        ml[1] = l;
    }
}

// Pass 2: exact cross-partial softmax combine. grid = B, block = 256.
// np = nchunk * kNW partials per batch.
__global__ __launch_bounds__(256)
void attn_combine(const float* __restrict__ acc_ws,
                  const float* __restrict__ ml_ws,
                  float* __restrict__ out,
                  int np)
{
    const int b = blockIdx.x;
    const int t = threadIdx.x;

    float M = -INFINITY;
    for (int p = 0; p < np; ++p)
        M = fmaxf(M, ml_ws[((size_t)b * np + p) * 2 + 0]);

    float L = 0.f;
    float4 o0 = {0.f, 0.f, 0.f, 0.f};
    float4 o1 = {0.f, 0.f, 0.f, 0.f};
    for (int p = 0; p < np; ++p) {
        const float mp = ml_ws[((size_t)b * np + p) * 2 + 0];
        const float lp = ml_ws[((size_t)b * np + p) * 2 + 1];
        const float coef = __expf(mp - M);
        L += lp * coef;
        const float* a = acc_ws + ((size_t)b * np + p) * kD;
        float4 a0 = *reinterpret_cast<const float4*>(a + 4 * t);
        float4 a1 = *reinterpret_cast<const float4*>(a + 1024 + 4 * t);
        o0.x += coef * a0.x; o0.y += coef * a0.y;
        o0.z += coef * a0.z; o0.w += coef * a0.w;
        o1.x += coef * a1.x; o1.y += coef * a1.y;
        o1.z += coef * a1.z; o1.w += coef * a1.w;
    }
    const float inv = 1.f / L;
    float* ob = out + (size_t)b * kD;
    float4 r0 = {o0.x * inv, o0.y * inv, o0.z * inv, o0.w * inv};
    float4 r1 = {o1.x * inv, o1.y * inv, o1.z * inv, o1.w * inv};
    *reinterpret_cast<float4*>(ob + 4 * t)        = r0;
    *reinterpret_cast<float4*>(ob + 1024 + 4 * t) = r1;
}

} // namespace

extern "C" void kernel_launch(void* const* d_in, const int* in_sizes, int n_in,
                              void* d_out, int out_size, void* d_ws, size_t ws_size,
                              hipStream_t stream) {
    const float* h = (const float*)d_in[0];   // decoder_hidden [B, D]
    const float* E = (const float*)d_in[1];   // encoder_states [B, S, D]
    float* out = (float*)d_out;

    // nchunk=16 -> 512 blocks = exactly 2 resident blocks/CU, no tail.
    // Halve if the workspace is too small (keeps cs a multiple of 8).
    int nchunk = 16;
    while (nchunk > 1 &&
           (size_t)kB * nchunk * kNW * (kD + 2) * sizeof(float) > ws_size)
        nchunk >>= 1;

    float* acc_ws = (float*)d_ws;                              // [B, nchunk, kNW, D]
    float* ml_ws  = acc_ws + (size_t)kB * nchunk * kNW * kD;   // [B, nchunk, kNW, 2]

    dim3 g1(nchunk, kB);
    attn_partial<<<g1, 256, 0, stream>>>(h, E, acc_ws, ml_ws, nchunk);
    attn_combine<<<kB, 256, 0, stream>>>(acc_ws, ml_ws, out, nchunk * kNW);
}

// Round 4
// 210.812 us; speedup vs baseline: 1.6457x; 1.0385x over previous
//
#include <hip/hip_runtime.h>
#include <math.h>

namespace {

constexpr int kB = 32;
constexpr int kS = 4096;
constexpr int kD = 2048;
constexpr int kNW = 4;   // waves per block

// Pass 1: single-read flash partial, pair-processed + register double-buffered.
// grid = (nchunk, B), block = 256 (4 independent waves; no __syncthreads).
// Wave w owns rows {w, w+4, ...}; a row lives entirely in the wave's registers
// (lane covers d = 256*k + 4*lane). Rows are processed in PAIRS so the two
// 6-step butterfly chains interleave (half the serial cross-lane cost) and the
// online-softmax rescale runs once per pair. Two pair-buffers rotate so 16
// row-loads are always in flight during compute.
__global__ __launch_bounds__(256, 2)
void attn_partial(const float* __restrict__ h,      // [B, D]
                  const float* __restrict__ E,      // [B, S, D]
                  float* __restrict__ acc_ws,       // [B, nchunk, kNW, D]
                  float* __restrict__ ml_ws,        // [B, nchunk, kNW, 2]
                  int nchunk)
{
    const int c    = blockIdx.x;
    const int b    = blockIdx.y;
    const int t    = threadIdx.x;
    const int lane = t & 63;
    const int wave = t >> 6;
    const int cs   = kS / nchunk;     // rows per chunk
    const int s0   = c * cs;
    const int P    = cs / kNW / 2;    // pairs per wave (even: >= 32)

    const float* hb = h + (size_t)b * kD;
    float4 hreg[8];
#pragma unroll
    for (int k = 0; k < 8; ++k)
        hreg[k] = *reinterpret_cast<const float4*>(hb + 256 * k + 4 * lane);

    float4 acc[8];
#pragma unroll
    for (int k = 0; k < 8; ++k) acc[k] = make_float4(0.f, 0.f, 0.f, 0.f);
    float m = -INFINITY, l = 0.f;

    // pair j covers per-wave rows 2j and 2j+1 -> global stride kNW*kD each
    const float* Eb = E + ((size_t)b * kS + s0 + wave) * kD + 4 * lane;

    float4 e0a[8], e0b[8], e1a[8], e1b[8];

#define LOADP(ra, rb, j)                                                     \
    {                                                                        \
        const float* _r0 = Eb + (size_t)(2 * (j)) * (kNW * kD);              \
        const float* _r1 = _r0 + (kNW * kD);                                 \
        _Pragma("unroll")                                                    \
        for (int k = 0; k < 8; ++k) {                                        \
            ra[k] = *reinterpret_cast<const float4*>(_r0 + 256 * k);         \
            rb[k] = *reinterpret_cast<const float4*>(_r1 + 256 * k);         \
        }                                                                    \
    }

#define COMPP(ra, rb)                                                        \
    {                                                                        \
        float pa = 0.f, pb = 0.f;                                            \
        _Pragma("unroll")                                                    \
        for (int k = 0; k < 8; ++k) {                                        \
            pa += ra[k].x * hreg[k].x + ra[k].y * hreg[k].y +                \
                  ra[k].z * hreg[k].z + ra[k].w * hreg[k].w;                 \
            pb += rb[k].x * hreg[k].x + rb[k].y * hreg[k].y +                \
                  rb[k].z * hreg[k].z + rb[k].w * hreg[k].w;                 \
        }                                                                    \
        _Pragma("unroll")                                                    \
        for (int off = 32; off > 0; off >>= 1) {                             \
            pa += __shfl_xor(pa, off, 64);                                   \
            pb += __shfl_xor(pb, off, 64);                                   \
        }                                                                    \
        const float mnew = fmaxf(m, fmaxf(pa, pb));  /* v_max3 */            \
        if (mnew > m) {              /* wave-uniform; rare */                \
            const float scale = __expf(m - mnew);                            \
            _Pragma("unroll")                                                \
            for (int k = 0; k < 8; ++k) {                                    \
                acc[k].x *= scale; acc[k].y *= scale;                        \
                acc[k].z *= scale; acc[k].w *= scale;                        \
            }                                                                \
            l *= scale;                                                      \
            m = mnew;                                                        \
        }                                                                    \
        const float wa = __expf(pa - m);                                     \
        const float wb = __expf(pb - m);                                     \
        l += wa + wb;                                                        \
        _Pragma("unroll")                                                    \
        for (int k = 0; k < 8; ++k) {                                        \
            acc[k].x += wa * ra[k].x + wb * rb[k].x;                         \
            acc[k].y += wa * ra[k].y + wb * rb[k].y;                         \
            acc[k].z += wa * ra[k].z + wb * rb[k].z;                         \
            acc[k].w += wa * ra[k].w + wb * rb[k].w;                         \
        }                                                                    \
    }

    // rotated 2-deep pair pipeline; P is even and >= 2
    LOADP(e0a, e0b, 0);
    LOADP(e1a, e1b, 1);
    for (int j = 0; j < P - 2; j += 2) {
        COMPP(e0a, e0b);
        LOADP(e0a, e0b, j + 2);
        COMPP(e1a, e1b);
        LOADP(e1a, e1b, j + 3);
    }
    COMPP(e0a, e0b);
    COMPP(e1a, e1b);

#undef LOADP
#undef COMPP

    float* aout = acc_ws + (((size_t)b * nchunk + c) * kNW + wave) * kD;
#pragma unroll
    for (int k = 0; k < 8; ++k)
        *reinterpret_cast<float4*>(aout + 256 * k + 4 * lane) = acc[k];
    if (lane == 0) {
        float* ml = ml_ws + (((size_t)b * nchunk + c) * kNW + wave) * 2;
        ml[0] = m;
        ml[1] = l;
    }
}

// Pass 2: exact cross-partial softmax combine, parallel over D slices.
// grid = (kD/256, B), block = 64 (one wave owns 256 columns).
__global__ __launch_bounds__(64)
void attn_combine(const float* __restrict__ acc_ws,
                  const float* __restrict__ ml_ws,
                  float* __restrict__ out,
                  int np)
{
    const int slice = blockIdx.x;           // 0..7
    const int b     = blockIdx.y;
    const int t     = threadIdx.x;          // 0..63
    const int col   = slice * 256 + 4 * t;

    const float* ml = ml_ws + (size_t)b * np * 2;
    float M = -INFINITY;
    for (int p = 0; p < np; ++p) M = fmaxf(M, ml[2 * p]);

    float L = 0.f;
    float4 o = {0.f, 0.f, 0.f, 0.f};
    for (int p = 0; p < np; ++p) {
        const float coef = __expf(ml[2 * p] - M);
        L += ml[2 * p + 1] * coef;
        const float4 a = *reinterpret_cast<const float4*>(
            acc_ws + ((size_t)b * np + p) * kD + col);
        o.x += coef * a.x; o.y += coef * a.y;
        o.z += coef * a.z; o.w += coef * a.w;
    }
    const float inv = 1.f / L;
    float4 r = {o.x * inv, o.y * inv, o.z * inv, o.w * inv};
    *reinterpret_cast<float4*>(out + (size_t)b * kD + col) = r;
}

} // namespace

extern "C" void kernel_launch(void* const* d_in, const int* in_sizes, int n_in,
                              void* d_out, int out_size, void* d_ws, size_t ws_size,
                              hipStream_t stream) {
    const float* h = (const float*)d_in[0];   // decoder_hidden [B, D]
    const float* E = (const float*)d_in[1];   // encoder_states [B, S, D]
    float* out = (float*)d_out;

    // nchunk=16 -> 512 blocks = exactly 2 resident blocks/CU, no tail.
    int nchunk = 16;
    while (nchunk > 1 &&
           (size_t)kB * nchunk * kNW * (kD + 2) * sizeof(float) > ws_size)
        nchunk >>= 1;

    float* acc_ws = (float*)d_ws;                              // [B, nchunk, kNW, D]
    float* ml_ws  = acc_ws + (size_t)kB * nchunk * kNW * kD;   // [B, nchunk, kNW, 2]

    dim3 g1(nchunk, kB);
    attn_partial<<<g1, 256, 0, stream>>>(h, E, acc_ws, ml_ws, nchunk);
    dim3 g2(kD / 256, kB);
    attn_combine<<<g2, 64, 0, stream>>>(acc_ws, ml_ws, out, nchunk * kNW);
}